// Round 5
// baseline (289.261 us; speedup 1.0000x reference)
//
#include <hip/hip_runtime.h>
#include <hip/hip_bf16.h>

#define BB 8
#define LL 4096
#define DM 96
#define DI 192
#define RRR 6
#define DHH 32
#define KKK 4
#define NNN 16
#define KRR 24
#define NCH 64
#define TT 64
#define RST 48   // rec record layout (floats): dt 0-5 | pad | dec 8-13 | pad | B 16-31 | C 32-47

__device__ __forceinline__ float softplus_f(float x){
    float ax = fabsf(x);
    return fmaxf(x, 0.f) + __logf(1.f + __expf(-ax));
}
__device__ __forceinline__ float silu_f(float x){ return x / (1.f + __expf(-x)); }

// ---------------- K0p: prep — WpR[192][160] reordered [dir0|dir2|dir1|dir3], wg, sg/bw ---------
// per-dir 40-col layout: dt 0-5, pad 6-7, B 8-23, C 24-39 (zeros in pads)
__global__ void k0p(const float* __restrict__ W, const float* __restrict__ g,
                    const float* __restrict__ bta, const float* __restrict__ w_out,
                    float* __restrict__ WpR, float* __restrict__ wg, float* __restrict__ sgbw){
    int i = blockIdx.x * 256 + threadIdx.x;
    if (i < DI * 160){
        int d = i / 160, cc = i % 160; int gq = cc / 40, nc = cc % 40;
        int dir = (gq == 0) ? 0 : (gq == 1) ? 2 : (gq == 2) ? 1 : 3;
        float v = 0.f;
        if (nc < 6) v = W[(dir * 38 + nc) * DI + d];
        else if (nc >= 8) v = W[(dir * 38 + (nc - 2)) * DI + d];
        WpR[i] = v;
    } else if (i < DI * 160 + DI * DM){
        int j = i - DI * 160; int c = j / DM;
        wg[j] = w_out[j] * g[c];
    } else if (i < DI * 160 + DI * DM + DM){
        int m = i - (DI * 160 + DI * DM);
        float s = 0.f, t = 0.f;
        for (int c = 0; c < DI; ++c){
            float w = w_out[c * DM + m];
            s = fmaf(g[c], w, s);
            t = fmaf(bta[c], w, t);
        }
        sgbw[m] = s; sgbw[DM + m] = t;
    }
}

// ---------------- K1 v2: xw = x @ w_in, 32-pix tiles, 1024 blocks ----------------
__global__ __launch_bounds__(384) void k1_inproj(const float* __restrict__ x,
                                                 const float* __restrict__ w_in,
                                                 float* __restrict__ xw){
    __shared__ float xT[DM][36];
    int pix0 = blockIdx.x * 32;
    for (int i = threadIdx.x; i < 32 * 24; i += 384){
        int c4 = i % 24, p = i / 24;
        float4 v = *(const float4*)(x + (size_t)(pix0 + p) * DM + c4 * 4);
        xT[c4 * 4 + 0][p] = v.x; xT[c4 * 4 + 1][p] = v.y;
        xT[c4 * 4 + 2][p] = v.z; xT[c4 * 4 + 3][p] = v.w;
    }
    __syncthreads();
    int cg = threadIdx.x % 48, pg = threadIdx.x / 48;   // 8 pixgroups(4 pix) x 48 cgroups
    int p0 = pg * 4;
    float4 acc[4];
    #pragma unroll
    for (int i = 0; i < 4; ++i) acc[i] = make_float4(0.f, 0.f, 0.f, 0.f);
    const float* wcol = w_in + cg * 4;
    for (int d = 0; d < DM; ++d){
        float4 w4 = *(const float4*)(wcol + d * DI);
        float4 xa = *(const float4*)(&xT[d][p0]);
        float xs[4] = {xa.x, xa.y, xa.z, xa.w};
        #pragma unroll
        for (int pi = 0; pi < 4; ++pi){
            acc[pi].x = fmaf(xs[pi], w4.x, acc[pi].x);
            acc[pi].y = fmaf(xs[pi], w4.y, acc[pi].y);
            acc[pi].z = fmaf(xs[pi], w4.z, acc[pi].z);
            acc[pi].w = fmaf(xs[pi], w4.w, acc[pi].w);
        }
    }
    #pragma unroll
    for (int pi = 0; pi < 4; ++pi)
        *(float4*)(xw + (size_t)(pix0 + p0 + pi) * DI + cg * 4) = acc[pi];
}

// ---------------- K2: xi = silu(dwconv3x3(xw) + b_conv); also write transposed xiT -----------
__global__ void k2_conv(const float* __restrict__ xw, const float* __restrict__ wc,
                        const float* __restrict__ bc, float* __restrict__ xi,
                        float* __restrict__ xiT){
    int gid = blockIdx.x * 256 + threadIdx.x;   // BB*LL*48 threads, float4 over channels
    int c4 = gid % 48; int pix = gid / 48;
    int b = pix >> 12; int l = pix & 4095; int h = l >> 6; int w = l & 63;
    int c = c4 * 4;
    float4 acc = *(const float4*)(bc + c);
    #pragma unroll
    for (int dh = 0; dh < 3; ++dh){
        int hh = h + dh - 1; if ((unsigned)hh >= 64u) continue;
        #pragma unroll
        for (int dw = 0; dw < 3; ++dw){
            int ww2 = w + dw - 1; if ((unsigned)ww2 >= 64u) continue;
            float4 tap = *(const float4*)(xw + (size_t)((b << 12) + (hh << 6) + ww2) * DI + c);
            float4 wv  = *(const float4*)(wc + (dh * 3 + dw) * DI + c);
            acc.x = fmaf(tap.x, wv.x, acc.x);
            acc.y = fmaf(tap.y, wv.y, acc.y);
            acc.z = fmaf(tap.z, wv.z, acc.z);
            acc.w = fmaf(tap.w, wv.w, acc.w);
        }
    }
    acc.x = silu_f(acc.x); acc.y = silu_f(acc.y); acc.z = silu_f(acc.z); acc.w = silu_f(acc.w);
    *(float4*)(xi + (size_t)pix * DI + c) = acc;
    int lT = ((l & 63) << 6) | (l >> 6);
    *(float4*)(xiT + (size_t)((b << 12) + lT) * DI + c) = acc;
}

// ---------------- K3seq v3: 32-pix tiles, 1024 blocks, all 4 dirs per tile ----------------
// 320 threads = 8 pixgroups(4 pix) x 40 colgroups(4 cols) = 160 cols.
// Write index per dir: 0 -> t=l, 2 -> t=L-1-l; 1 -> t=lT, 3 -> t=L-1-lT.
__global__ __launch_bounds__(320) void k3seq(const float* __restrict__ xi,
                                             const float* __restrict__ WpR,
                                             const float* __restrict__ A_logs,
                                             const float* __restrict__ dtb,
                                             float* __restrict__ rec){
    __shared__ float xT[96][36];
    int b = blockIdx.y;
    int l0 = blockIdx.x * 32;
    const float* src = xi + ((((size_t)b) << 12) + l0) * DI;
    int kg = threadIdx.x % 40, pg = threadIdx.x / 40;
    int p0 = pg * 4;
    float4 acc[4];
    #pragma unroll
    for (int i = 0; i < 4; ++i) acc[i] = make_float4(0.f, 0.f, 0.f, 0.f);
    const float* wcol = WpR + kg * 4;
    #pragma unroll
    for (int half = 0; half < 2; ++half){
        __syncthreads();
        for (int i = threadIdx.x; i < 32 * 24; i += 320){
            int c4 = i % 24, p = i / 24;
            float4 v = *(const float4*)(src + (size_t)p * DI + half * 96 + c4 * 4);
            xT[c4 * 4 + 0][p] = v.x; xT[c4 * 4 + 1][p] = v.y;
            xT[c4 * 4 + 2][p] = v.z; xT[c4 * 4 + 3][p] = v.w;
        }
        __syncthreads();
        const float* w = wcol + half * 96 * 160;
        for (int d = 0; d < 96; ++d){
            float4 w4 = *(const float4*)(w + d * 160);
            float4 xa = *(const float4*)(&xT[d][p0]);
            float xs[4] = {xa.x, xa.y, xa.z, xa.w};
            #pragma unroll
            for (int pi = 0; pi < 4; ++pi){
                acc[pi].x = fmaf(xs[pi], w4.x, acc[pi].x);
                acc[pi].y = fmaf(xs[pi], w4.y, acc[pi].y);
                acc[pi].z = fmaf(xs[pi], w4.z, acc[pi].z);
                acc[pi].w = fmaf(xs[pi], w4.w, acc[pi].w);
            }
        }
    }
    int gq = kg / 10;
    int dir = (gq == 0) ? 0 : (gq == 1) ? 2 : (gq == 2) ? 1 : 3;
    int nc0 = (kg % 10) * 4;
    float* rb = rec + (size_t)(b * KKK + dir) * LL * RST;
    float A0 = 0.f, A1 = 0.f, A2 = 0.f, A3 = 0.f, b0 = 0.f, b1 = 0.f, b2 = 0.f, b3 = 0.f;
    if (nc0 == 0){
        A0 = -__expf(A_logs[dir * RRR + 0]); b0 = dtb[dir * RRR + 0];
        A1 = -__expf(A_logs[dir * RRR + 1]); b1 = dtb[dir * RRR + 1];
        A2 = -__expf(A_logs[dir * RRR + 2]); b2 = dtb[dir * RRR + 2];
        A3 = -__expf(A_logs[dir * RRR + 3]); b3 = dtb[dir * RRR + 3];
    } else if (nc0 == 4){
        A0 = -__expf(A_logs[dir * RRR + 4]); b0 = dtb[dir * RRR + 4];
        A1 = -__expf(A_logs[dir * RRR + 5]); b1 = dtb[dir * RRR + 5];
    }
    #pragma unroll
    for (int pi = 0; pi < 4; ++pi){
        int l = l0 + p0 + pi;
        int lT = ((l & 63) << 6) | (l >> 6);
        int t;
        if (dir == 0) t = l;
        else if (dir == 2) t = LL - 1 - l;
        else if (dir == 1) t = lT;
        else t = LL - 1 - lT;
        float* rw = rb + (size_t)t * RST;
        float4 v = acc[pi];
        if (nc0 == 0){
            float4 dt4, dc4;
            dt4.x = softplus_f(v.x + b0); dc4.x = __expf(dt4.x * A0);
            dt4.y = softplus_f(v.y + b1); dc4.y = __expf(dt4.y * A1);
            dt4.z = softplus_f(v.z + b2); dc4.z = __expf(dt4.z * A2);
            dt4.w = softplus_f(v.w + b3); dc4.w = __expf(dt4.w * A3);
            *(float4*)(rw + 0) = dt4;
            *(float4*)(rw + 8) = dc4;
        } else if (nc0 == 4){
            float4 dt4, dc4;
            dt4.x = softplus_f(v.x + b0); dc4.x = __expf(dt4.x * A0);
            dt4.y = softplus_f(v.y + b1); dc4.y = __expf(dt4.y * A1);
            dt4.z = 0.f; dt4.w = 0.f; dc4.z = 0.f; dc4.w = 0.f;
            *(float4*)(rw + 4)  = dt4;
            *(float4*)(rw + 12) = dc4;
        } else {
            *(float4*)(rw + nc0 + 8) = v;   // B: cols 8-23 -> slots 16-31; C: 24-39 -> 32-47
        }
    }
}

// ---------------- K4a: per-chunk local scan -> P, S  (all streams constant-stride) ------------
__global__ __launch_bounds__(192) void k4a(const float* __restrict__ xi, const float* __restrict__ xiT,
                                           const float* __restrict__ rec,
                                           float* __restrict__ Pb, float* __restrict__ Sb){
    int chunk = blockIdx.x, k = blockIdx.y, b = blockIdx.z;
    int r = threadIdx.x >> 5, d = threadIdx.x & 31;
    int kr = k * RRR + r;
    const float* rp = rec + ((size_t)(b * KKK + k) * LL + chunk * TT) * RST;
    const float* xb = ((k & 1) ? xiT : xi) + (((size_t)b) << 12) * DI + r * DHH + d;
    const float* up; ptrdiff_t ust;
    if (k < 2){ up = xb + (size_t)(chunk * TT) * DI;          ust = DI;  }
    else      { up = xb + (size_t)(LL - 1 - chunk * TT) * DI; ust = -(ptrdiff_t)DI; }
    float h[NNN];
    #pragma unroll
    for (int n = 0; n < NNN; ++n) h[n] = 0.f;
    float P = 1.f;
    #pragma unroll 4
    for (int tt = 0; tt < TT; ++tt){
        float dt  = rp[r];
        float dec = rp[8 + r];
        float u = *up;
        float xu = dt * u;
        P *= dec;
        float Bv[NNN];
        *(float4*)(Bv + 0)  = *(const float4*)(rp + 16);
        *(float4*)(Bv + 4)  = *(const float4*)(rp + 20);
        *(float4*)(Bv + 8)  = *(const float4*)(rp + 24);
        *(float4*)(Bv + 12) = *(const float4*)(rp + 28);
        #pragma unroll
        for (int n = 0; n < NNN; ++n) h[n] = fmaf(dec, h[n], xu * Bv[n]);
        rp += RST; up += ust;
    }
    size_t sb = (((size_t)(b * KRR + kr) * NCH + chunk) * DHH + d) * NNN;
    #pragma unroll
    for (int n = 0; n < NNN; ++n) Sb[sb + n] = h[n];
    if (d == 0) Pb[(size_t)(b * KRR + kr) * NCH + chunk] = P;
}

// ---------------- K4b: cross-chunk exclusive scan (in-place), split grid ----------------
__global__ __launch_bounds__(256) void k4b(const float* __restrict__ Pb, float* __restrict__ Sb){
    int scan = blockIdx.x >> 1;        // b*KRR + kr
    int half = blockIdx.x & 1;
    int tid = half * 256 + threadIdx.x;   // 512 = d*16 + n
    size_t base = (size_t)scan * NCH * 512 + tid;
    const float* Pp = Pb + (size_t)scan * NCH;
    float s[NCH];
    #pragma unroll
    for (int c = 0; c < NCH; ++c) s[c] = Sb[base + (size_t)c * 512];
    float hb = 0.f;
    #pragma unroll
    for (int c = 0; c < NCH; ++c){
        float nv = fmaf(Pp[c], hb, s[c]);
        Sb[base + (size_t)c * 512] = hb;
        hb = nv;
    }
}

// ---------------- K4c: replay from h_init, emit y in sequence order (bf16) ----------------
__global__ __launch_bounds__(192) void k4c(const float* __restrict__ xi, const float* __restrict__ xiT,
                                           const float* __restrict__ rec,
                                           const float* __restrict__ Ds, const float* __restrict__ Sb,
                                           __hip_bfloat16* __restrict__ ybuf){
    int chunk = blockIdx.x, k = blockIdx.y, b = blockIdx.z;
    int r = threadIdx.x >> 5, d = threadIdx.x & 31;
    int kr = k * RRR + r;
    float Dv = Ds[kr * DHH + d];
    float h[NNN];
    size_t sb = (((size_t)(b * KRR + kr) * NCH + chunk) * DHH + d) * NNN;
    #pragma unroll
    for (int n = 0; n < NNN; ++n) h[n] = Sb[sb + n];
    const float* rp = rec + ((size_t)(b * KKK + k) * LL + chunk * TT) * RST;
    const float* xb = ((k & 1) ? xiT : xi) + (((size_t)b) << 12) * DI + r * DHH + d;
    const float* up; ptrdiff_t ust;
    if (k < 2){ up = xb + (size_t)(chunk * TT) * DI;          ust = DI;  }
    else      { up = xb + (size_t)(LL - 1 - chunk * TT) * DI; ust = -(ptrdiff_t)DI; }
    __hip_bfloat16* yp = ybuf + ((size_t)(k * BB + b) * LL + chunk * TT) * DI + r * DHH + d;
    #pragma unroll 2
    for (int tt = 0; tt < TT; ++tt){
        float dt  = rp[r];
        float dec = rp[8 + r];
        float u = *up;
        float xu = dt * u;
        float Bv[NNN], Cv[NNN];
        *(float4*)(Bv + 0)  = *(const float4*)(rp + 16);
        *(float4*)(Bv + 4)  = *(const float4*)(rp + 20);
        *(float4*)(Bv + 8)  = *(const float4*)(rp + 24);
        *(float4*)(Bv + 12) = *(const float4*)(rp + 28);
        *(float4*)(Cv + 0)  = *(const float4*)(rp + 32);
        *(float4*)(Cv + 4)  = *(const float4*)(rp + 36);
        *(float4*)(Cv + 8)  = *(const float4*)(rp + 40);
        *(float4*)(Cv + 12) = *(const float4*)(rp + 44);
        float y = 0.f;
        #pragma unroll
        for (int n = 0; n < NNN; ++n){
            h[n] = fmaf(dec, h[n], xu * Bv[n]);
            y = fmaf(h[n], Cv[n], y);
        }
        y = fmaf(u, Dv, y);
        *yp = __float2bfloat16(y);
        rp += RST; up += ust; yp += DI;
    }
}

// ---------------- K5: gather 4 sequence-ordered y's + fused LayerNorm + out-proj ----------------
__global__ __launch_bounds__(256) void k5_out(const __hip_bfloat16* __restrict__ ybuf,
                       const float* __restrict__ wg, const float* __restrict__ sgbw,
                       float* __restrict__ out){
    __shared__ float yT[DI][36];
    __shared__ float rsL[32], rmL[32];
    int pix0 = blockIdx.x * 32;
    int b = pix0 >> 12;
    int l0 = pix0 & 4095;
    const __hip_bfloat16* y0 = ybuf + (size_t)(0 * BB + b) * LL * DI;
    const __hip_bfloat16* y1 = ybuf + (size_t)(1 * BB + b) * LL * DI;
    const __hip_bfloat16* y2 = ybuf + (size_t)(2 * BB + b) * LL * DI;
    const __hip_bfloat16* y3 = ybuf + (size_t)(3 * BB + b) * LL * DI;
    for (int i = threadIdx.x; i < 32 * DI; i += 256){
        int c = i % DI, p = i / DI;
        int l = l0 + p; int hh = l >> 6, ww = l & 63;
        int lT = (ww << 6) | hh;
        float s = __bfloat162float(y0[(size_t)l * DI + c])
                + __bfloat162float(y2[(size_t)(LL - 1 - l) * DI + c])
                + __bfloat162float(y1[(size_t)lT * DI + c])
                + __bfloat162float(y3[(size_t)(LL - 1 - lT) * DI + c]);
        yT[c][p] = s;
    }
    __syncthreads();
    {
        int p = threadIdx.x >> 3, cg = threadIdx.x & 7;
        float s = 0.f, s2 = 0.f;
        for (int c = cg; c < DI; c += 8){ float v = yT[c][p]; s += v; s2 = fmaf(v, v, s2); }
        s += __shfl_xor(s, 1, 64); s2 += __shfl_xor(s2, 1, 64);
        s += __shfl_xor(s, 2, 64); s2 += __shfl_xor(s2, 2, 64);
        s += __shfl_xor(s, 4, 64); s2 += __shfl_xor(s2, 4, 64);
        if (cg == 0){
            float mu = s * (1.f / DI);
            float var = s2 * (1.f / DI) - mu * mu;
            float rs = rsqrtf(var + 1e-5f);
            rsL[p] = rs; rmL[p] = rs * mu;
        }
    }
    __syncthreads();
    if (threadIdx.x < 192){
        int mg = threadIdx.x % 24, pg = threadIdx.x / 24;  // 8 pixgroups x 24 mgroups
        int p0 = pg * 4;
        float4 acc[4];
        #pragma unroll
        for (int i = 0; i < 4; ++i) acc[i] = make_float4(0.f, 0.f, 0.f, 0.f);
        const float* wcol = wg + mg * 4;
        for (int c = 0; c < DI; ++c){
            float4 w4 = *(const float4*)(wcol + c * DM);
            float4 yv = *(const float4*)(&yT[c][p0]);
            float ys[4] = {yv.x, yv.y, yv.z, yv.w};
            #pragma unroll
            for (int pi = 0; pi < 4; ++pi){
                acc[pi].x = fmaf(ys[pi], w4.x, acc[pi].x);
                acc[pi].y = fmaf(ys[pi], w4.y, acc[pi].y);
                acc[pi].z = fmaf(ys[pi], w4.z, acc[pi].z);
                acc[pi].w = fmaf(ys[pi], w4.w, acc[pi].w);
            }
        }
        float4 sg4 = *(const float4*)(sgbw + mg * 4);
        float4 bw4 = *(const float4*)(sgbw + DM + mg * 4);
        #pragma unroll
        for (int pi = 0; pi < 4; ++pi){
            float rs = rsL[p0 + pi], rm = rmL[p0 + pi];
            float4 o;
            o.x = fmaf(acc[pi].x, rs, fmaf(-rm, sg4.x, bw4.x));
            o.y = fmaf(acc[pi].y, rs, fmaf(-rm, sg4.y, bw4.y));
            o.z = fmaf(acc[pi].z, rs, fmaf(-rm, sg4.z, bw4.z));
            o.w = fmaf(acc[pi].w, rs, fmaf(-rm, sg4.w, bw4.w));
            *(float4*)(out + (size_t)(pix0 + p0 + pi) * DM + mg * 4) = o;
        }
    }
}

extern "C" void kernel_launch(void* const* d_in, const int* in_sizes, int n_in,
                              void* d_out, int out_size, void* d_ws, size_t ws_size,
                              hipStream_t stream){
    const float* x      = (const float*)d_in[0];
    const float* w_in   = (const float*)d_in[1];
    const float* w_conv = (const float*)d_in[2];
    const float* b_conv = (const float*)d_in[3];
    const float* xproj  = (const float*)d_in[4];
    const float* A_logs = (const float*)d_in[5];
    const float* Ds     = (const float*)d_in[6];
    const float* dtbias = (const float*)d_in[7];
    const float* ln_g   = (const float*)d_in[8];
    const float* ln_b   = (const float*)d_in[9];
    const float* w_out  = (const float*)d_in[10];
    float* out = (float*)d_out;

    // workspace layout (floats):
    float* ws   = (float*)d_ws;
    float* xi   = ws;                      // 6,291,456
    float* xiT  = xi + 6291456;            // 6,291,456
    float* Sb   = xiT + 6291456;           // 6,291,456
    float* Pb   = Sb + 6291456;            // 16,384
    float* WpR  = Pb + 16384;              // 30,720
    float* wg   = WpR + 30720;             // 18,432
    float* sgbw = wg + 18432;              // 192
    float* big  = sgbw + 192;              // union: xw (6,291,456) / rec (6,291,456)
    float* xw   = big;
    float* rec  = big;
    __hip_bfloat16* ybuf = (__hip_bfloat16*)(big + 6291456);  // 25,165,824 bf16

    k0p<<<193, 256, 0, stream>>>(xproj, ln_g, ln_b, w_out, WpR, wg, sgbw);
    k1_inproj<<<1024, 384, 0, stream>>>(x, w_in, xw);
    k2_conv<<<6144, 256, 0, stream>>>(xw, w_conv, b_conv, xi, xiT);
    k3seq<<<dim3(128, BB), 320, 0, stream>>>(xi, WpR, A_logs, dtbias, rec);
    k4a<<<dim3(NCH, KKK, BB), 192, 0, stream>>>(xi, xiT, rec, Pb, Sb);
    k4b<<<384, 256, 0, stream>>>(Pb, Sb);
    k4c<<<dim3(NCH, KKK, BB), 192, 0, stream>>>(xi, xiT, rec, Ds, Sb, ybuf);
    k5_out<<<1024, 256, 0, stream>>>(ybuf, wg, sgbw, out);
}

// Round 6
// 283.667 us; speedup vs baseline: 1.0197x; 1.0197x over previous
//
#include <hip/hip_runtime.h>
#include <hip/hip_bf16.h>

#define BB 8
#define LL 4096
#define DM 96
#define DI 192
#define RRR 6
#define DHH 32
#define KKK 4
#define NNN 16
#define KRR 24
#define NCH 64
#define TT 64
#define RST 48   // rec record layout (floats): dt 0-5 | pad | dec 8-13 | pad | B 16-31 | C 32-47

__device__ __forceinline__ float softplus_f(float x){
    float ax = fabsf(x);
    return fmaxf(x, 0.f) + __logf(1.f + __expf(-ax));
}
__device__ __forceinline__ float silu_f(float x){ return x / (1.f + __expf(-x)); }

// ---------------- K0p: prep — WpR[192][160] reordered [dir0|dir2|dir1|dir3], wg, sg/bw ---------
// per-dir 40-col layout: dt 0-5, pad 6-7, B 8-23, C 24-39 (zeros in pads)
__global__ void k0p(const float* __restrict__ W, const float* __restrict__ g,
                    const float* __restrict__ bta, const float* __restrict__ w_out,
                    float* __restrict__ WpR, float* __restrict__ wg, float* __restrict__ sgbw){
    int i = blockIdx.x * 256 + threadIdx.x;
    if (i < DI * 160){
        int d = i / 160, cc = i % 160; int gq = cc / 40, nc = cc % 40;
        int dir = (gq == 0) ? 0 : (gq == 1) ? 2 : (gq == 2) ? 1 : 3;
        float v = 0.f;
        if (nc < 6) v = W[(dir * 38 + nc) * DI + d];
        else if (nc >= 8) v = W[(dir * 38 + (nc - 2)) * DI + d];
        WpR[i] = v;
    } else if (i < DI * 160 + DI * DM){
        int j = i - DI * 160; int c = j / DM;
        wg[j] = w_out[j] * g[c];
    } else if (i < DI * 160 + DI * DM + DM){
        int m = i - (DI * 160 + DI * DM);
        float s = 0.f, t = 0.f;
        for (int c = 0; c < DI; ++c){
            float w = w_out[c * DM + m];
            s = fmaf(g[c], w, s);
            t = fmaf(bta[c], w, t);
        }
        sgbw[m] = s; sgbw[DM + m] = t;
    }
}

// ---------------- K1 v3: xw = x @ w_in, 32-pix tiles, batch-8 load pipelining ----------------
__global__ __launch_bounds__(384) void k1_inproj(const float* __restrict__ x,
                                                 const float* __restrict__ w_in,
                                                 float* __restrict__ xw){
    __shared__ float xT[DM][36];
    int pix0 = blockIdx.x * 32;
    for (int i = threadIdx.x; i < 32 * 24; i += 384){
        int c4 = i % 24, p = i / 24;
        float4 v = *(const float4*)(x + (size_t)(pix0 + p) * DM + c4 * 4);
        xT[c4 * 4 + 0][p] = v.x; xT[c4 * 4 + 1][p] = v.y;
        xT[c4 * 4 + 2][p] = v.z; xT[c4 * 4 + 3][p] = v.w;
    }
    __syncthreads();
    int cg = threadIdx.x % 48, pg = threadIdx.x / 48;   // 8 pixgroups(4 pix) x 48 cgroups
    int p0 = pg * 4;
    float4 acc[4];
    #pragma unroll
    for (int i = 0; i < 4; ++i) acc[i] = make_float4(0.f, 0.f, 0.f, 0.f);
    const float* wcol = w_in + cg * 4;
    for (int d0 = 0; d0 < DM; d0 += 8){
        float4 wv[8], xv[8];
        #pragma unroll
        for (int j = 0; j < 8; ++j){
            wv[j] = *(const float4*)(wcol + (d0 + j) * DI);
            xv[j] = *(const float4*)(&xT[d0 + j][p0]);
        }
        #pragma unroll
        for (int j = 0; j < 8; ++j){
            float xs[4] = {xv[j].x, xv[j].y, xv[j].z, xv[j].w};
            #pragma unroll
            for (int pi = 0; pi < 4; ++pi){
                acc[pi].x = fmaf(xs[pi], wv[j].x, acc[pi].x);
                acc[pi].y = fmaf(xs[pi], wv[j].y, acc[pi].y);
                acc[pi].z = fmaf(xs[pi], wv[j].z, acc[pi].z);
                acc[pi].w = fmaf(xs[pi], wv[j].w, acc[pi].w);
            }
        }
    }
    #pragma unroll
    for (int pi = 0; pi < 4; ++pi)
        *(float4*)(xw + (size_t)(pix0 + p0 + pi) * DI + cg * 4) = acc[pi];
}

// ---------------- K2: xi = silu(dwconv3x3(xw) + b_conv); also write transposed xiT -----------
__global__ void k2_conv(const float* __restrict__ xw, const float* __restrict__ wc,
                        const float* __restrict__ bc, float* __restrict__ xi,
                        float* __restrict__ xiT){
    int gid = blockIdx.x * 256 + threadIdx.x;   // BB*LL*48 threads, float4 over channels
    int c4 = gid % 48; int pix = gid / 48;
    int b = pix >> 12; int l = pix & 4095; int h = l >> 6; int w = l & 63;
    int c = c4 * 4;
    float4 acc = *(const float4*)(bc + c);
    #pragma unroll
    for (int dh = 0; dh < 3; ++dh){
        int hh = h + dh - 1; if ((unsigned)hh >= 64u) continue;
        #pragma unroll
        for (int dw = 0; dw < 3; ++dw){
            int ww2 = w + dw - 1; if ((unsigned)ww2 >= 64u) continue;
            float4 tap = *(const float4*)(xw + (size_t)((b << 12) + (hh << 6) + ww2) * DI + c);
            float4 wv  = *(const float4*)(wc + (dh * 3 + dw) * DI + c);
            acc.x = fmaf(tap.x, wv.x, acc.x);
            acc.y = fmaf(tap.y, wv.y, acc.y);
            acc.z = fmaf(tap.z, wv.z, acc.z);
            acc.w = fmaf(tap.w, wv.w, acc.w);
        }
    }
    acc.x = silu_f(acc.x); acc.y = silu_f(acc.y); acc.z = silu_f(acc.z); acc.w = silu_f(acc.w);
    *(float4*)(xi + (size_t)pix * DI + c) = acc;
    int lT = ((l & 63) << 6) | (l >> 6);
    *(float4*)(xiT + (size_t)((b << 12) + lT) * DI + c) = acc;
}

// ---------------- K3seq v4: z=0: xi tile -> dirs{0,2}; z=1: xiT tile -> dirs{1,3} -------------
// 64-pix tiles, 320 threads = 16 pixgroups(4 pix) x 20 colgroups(4 cols) = 80 cols.
// All rec writes contiguous in t. Batch-8 load pipelining in the GEMM loop.
__global__ __launch_bounds__(320) void k3seq(const float* __restrict__ xi,
                                             const float* __restrict__ xiT,
                                             const float* __restrict__ WpR,
                                             const float* __restrict__ A_logs,
                                             const float* __restrict__ dtb,
                                             float* __restrict__ rec){
    __shared__ float xT[96][68];
    int z = blockIdx.y, b = blockIdx.z;
    int l0 = blockIdx.x * 64;
    const float* src = (z ? xiT : xi) + ((((size_t)b) << 12) + l0) * DI;
    int kg = threadIdx.x % 20, pg = threadIdx.x / 20;
    int p0 = pg * 4;
    float4 acc[4];
    #pragma unroll
    for (int i = 0; i < 4; ++i) acc[i] = make_float4(0.f, 0.f, 0.f, 0.f);
    const float* wcol = WpR + z * 80 + kg * 4;
    #pragma unroll
    for (int half = 0; half < 2; ++half){
        __syncthreads();
        for (int i = threadIdx.x; i < 64 * 24; i += 320){
            int c4 = i % 24, p = i / 24;
            float4 v = *(const float4*)(src + (size_t)p * DI + half * 96 + c4 * 4);
            xT[c4 * 4 + 0][p] = v.x; xT[c4 * 4 + 1][p] = v.y;
            xT[c4 * 4 + 2][p] = v.z; xT[c4 * 4 + 3][p] = v.w;
        }
        __syncthreads();
        const float* wp = wcol + half * 96 * 160;
        for (int d0 = 0; d0 < 96; d0 += 8){
            float4 wv[8], xv[8];
            #pragma unroll
            for (int j = 0; j < 8; ++j){
                wv[j] = *(const float4*)(wp + (d0 + j) * 160);
                xv[j] = *(const float4*)(&xT[d0 + j][p0]);
            }
            #pragma unroll
            for (int j = 0; j < 8; ++j){
                float xs[4] = {xv[j].x, xv[j].y, xv[j].z, xv[j].w};
                #pragma unroll
                for (int pi = 0; pi < 4; ++pi){
                    acc[pi].x = fmaf(xs[pi], wv[j].x, acc[pi].x);
                    acc[pi].y = fmaf(xs[pi], wv[j].y, acc[pi].y);
                    acc[pi].z = fmaf(xs[pi], wv[j].z, acc[pi].z);
                    acc[pi].w = fmaf(xs[pi], wv[j].w, acc[pi].w);
                }
            }
        }
    }
    int sub = kg / 10;                     // 0: first dir of this source, 1: reversed dir
    int dir = (z == 0) ? (sub == 0 ? 0 : 2) : (sub == 0 ? 1 : 3);
    int nc0 = (kg % 10) * 4;
    float* rb = rec + (size_t)(b * KKK + dir) * LL * RST;
    float A0 = 0.f, A1 = 0.f, A2 = 0.f, A3 = 0.f, b0 = 0.f, b1 = 0.f, b2 = 0.f, b3 = 0.f;
    if (nc0 == 0){
        A0 = -__expf(A_logs[dir * RRR + 0]); b0 = dtb[dir * RRR + 0];
        A1 = -__expf(A_logs[dir * RRR + 1]); b1 = dtb[dir * RRR + 1];
        A2 = -__expf(A_logs[dir * RRR + 2]); b2 = dtb[dir * RRR + 2];
        A3 = -__expf(A_logs[dir * RRR + 3]); b3 = dtb[dir * RRR + 3];
    } else if (nc0 == 4){
        A0 = -__expf(A_logs[dir * RRR + 4]); b0 = dtb[dir * RRR + 4];
        A1 = -__expf(A_logs[dir * RRR + 5]); b1 = dtb[dir * RRR + 5];
    }
    #pragma unroll
    for (int pi = 0; pi < 4; ++pi){
        int l = l0 + p0 + pi;              // index in this source's own order = seq pos of fwd dir
        int t = (sub == 0) ? l : (LL - 1 - l);
        float* rw = rb + (size_t)t * RST;
        float4 v = acc[pi];
        if (nc0 == 0){
            float4 dt4, dc4;
            dt4.x = softplus_f(v.x + b0); dc4.x = __expf(dt4.x * A0);
            dt4.y = softplus_f(v.y + b1); dc4.y = __expf(dt4.y * A1);
            dt4.z = softplus_f(v.z + b2); dc4.z = __expf(dt4.z * A2);
            dt4.w = softplus_f(v.w + b3); dc4.w = __expf(dt4.w * A3);
            *(float4*)(rw + 0) = dt4;
            *(float4*)(rw + 8) = dc4;
        } else if (nc0 == 4){
            float4 dt4, dc4;
            dt4.x = softplus_f(v.x + b0); dc4.x = __expf(dt4.x * A0);
            dt4.y = softplus_f(v.y + b1); dc4.y = __expf(dt4.y * A1);
            dt4.z = 0.f; dt4.w = 0.f; dc4.z = 0.f; dc4.w = 0.f;
            *(float4*)(rw + 4)  = dt4;
            *(float4*)(rw + 12) = dc4;
        } else {
            *(float4*)(rw + nc0 + 8) = v;   // B: cols 8-23 -> slots 16-31; C: 24-39 -> 32-47
        }
    }
}

// ---------------- K4a: per-chunk local scan -> P, S  (all streams constant-stride) ------------
__global__ __launch_bounds__(192) void k4a(const float* __restrict__ xi, const float* __restrict__ xiT,
                                           const float* __restrict__ rec,
                                           float* __restrict__ Pb, float* __restrict__ Sb){
    int chunk = blockIdx.x, k = blockIdx.y, b = blockIdx.z;
    int r = threadIdx.x >> 5, d = threadIdx.x & 31;
    int kr = k * RRR + r;
    const float* rp = rec + ((size_t)(b * KKK + k) * LL + chunk * TT) * RST;
    const float* xb = ((k & 1) ? xiT : xi) + (((size_t)b) << 12) * DI + r * DHH + d;
    const float* up; ptrdiff_t ust;
    if (k < 2){ up = xb + (size_t)(chunk * TT) * DI;          ust = DI;  }
    else      { up = xb + (size_t)(LL - 1 - chunk * TT) * DI; ust = -(ptrdiff_t)DI; }
    float h[NNN];
    #pragma unroll
    for (int n = 0; n < NNN; ++n) h[n] = 0.f;
    float P = 1.f;
    #pragma unroll 4
    for (int tt = 0; tt < TT; ++tt){
        float dt  = rp[r];
        float dec = rp[8 + r];
        float u = *up;
        float xu = dt * u;
        P *= dec;
        float Bv[NNN];
        *(float4*)(Bv + 0)  = *(const float4*)(rp + 16);
        *(float4*)(Bv + 4)  = *(const float4*)(rp + 20);
        *(float4*)(Bv + 8)  = *(const float4*)(rp + 24);
        *(float4*)(Bv + 12) = *(const float4*)(rp + 28);
        #pragma unroll
        for (int n = 0; n < NNN; ++n) h[n] = fmaf(dec, h[n], xu * Bv[n]);
        rp += RST; up += ust;
    }
    size_t sb = (((size_t)(b * KRR + kr) * NCH + chunk) * DHH + d) * NNN;
    #pragma unroll
    for (int n = 0; n < NNN; ++n) Sb[sb + n] = h[n];
    if (d == 0) Pb[(size_t)(b * KRR + kr) * NCH + chunk] = P;
}

// ---------------- K4b: cross-chunk exclusive scan (in-place), split grid ----------------
__global__ __launch_bounds__(256) void k4b(const float* __restrict__ Pb, float* __restrict__ Sb){
    int scan = blockIdx.x >> 1;        // b*KRR + kr
    int half = blockIdx.x & 1;
    int tid = half * 256 + threadIdx.x;   // 512 = d*16 + n
    size_t base = (size_t)scan * NCH * 512 + tid;
    const float* Pp = Pb + (size_t)scan * NCH;
    float s[NCH];
    #pragma unroll
    for (int c = 0; c < NCH; ++c) s[c] = Sb[base + (size_t)c * 512];
    float hb = 0.f;
    #pragma unroll
    for (int c = 0; c < NCH; ++c){
        float nv = fmaf(Pp[c], hb, s[c]);
        Sb[base + (size_t)c * 512] = hb;
        hb = nv;
    }
}

// ---------------- K4c: replay from h_init, emit y in sequence order (bf16) ----------------
__global__ __launch_bounds__(192) void k4c(const float* __restrict__ xi, const float* __restrict__ xiT,
                                           const float* __restrict__ rec,
                                           const float* __restrict__ Ds, const float* __restrict__ Sb,
                                           __hip_bfloat16* __restrict__ ybuf){
    int chunk = blockIdx.x, k = blockIdx.y, b = blockIdx.z;
    int r = threadIdx.x >> 5, d = threadIdx.x & 31;
    int kr = k * RRR + r;
    float Dv = Ds[kr * DHH + d];
    float h[NNN];
    size_t sb = (((size_t)(b * KRR + kr) * NCH + chunk) * DHH + d) * NNN;
    #pragma unroll
    for (int n = 0; n < NNN; ++n) h[n] = Sb[sb + n];
    const float* rp = rec + ((size_t)(b * KKK + k) * LL + chunk * TT) * RST;
    const float* xb = ((k & 1) ? xiT : xi) + (((size_t)b) << 12) * DI + r * DHH + d;
    const float* up; ptrdiff_t ust;
    if (k < 2){ up = xb + (size_t)(chunk * TT) * DI;          ust = DI;  }
    else      { up = xb + (size_t)(LL - 1 - chunk * TT) * DI; ust = -(ptrdiff_t)DI; }
    __hip_bfloat16* yp = ybuf + ((size_t)(k * BB + b) * LL + chunk * TT) * DI + r * DHH + d;
    #pragma unroll 2
    for (int tt = 0; tt < TT; ++tt){
        float dt  = rp[r];
        float dec = rp[8 + r];
        float u = *up;
        float xu = dt * u;
        float Bv[NNN], Cv[NNN];
        *(float4*)(Bv + 0)  = *(const float4*)(rp + 16);
        *(float4*)(Bv + 4)  = *(const float4*)(rp + 20);
        *(float4*)(Bv + 8)  = *(const float4*)(rp + 24);
        *(float4*)(Bv + 12) = *(const float4*)(rp + 28);
        *(float4*)(Cv + 0)  = *(const float4*)(rp + 32);
        *(float4*)(Cv + 4)  = *(const float4*)(rp + 36);
        *(float4*)(Cv + 8)  = *(const float4*)(rp + 40);
        *(float4*)(Cv + 12) = *(const float4*)(rp + 44);
        float y = 0.f;
        #pragma unroll
        for (int n = 0; n < NNN; ++n){
            h[n] = fmaf(dec, h[n], xu * Bv[n]);
            y = fmaf(h[n], Cv[n], y);
        }
        y = fmaf(u, Dv, y);
        *yp = __float2bfloat16(y);
        rp += RST; up += ust; yp += DI;
    }
}

// ---------------- K5: gather 4 sequence-ordered y's + fused LayerNorm + out-proj ----------------
__global__ __launch_bounds__(256) void k5_out(const __hip_bfloat16* __restrict__ ybuf,
                       const float* __restrict__ wg, const float* __restrict__ sgbw,
                       float* __restrict__ out){
    __shared__ float yT[DI][36];
    __shared__ float rsL[32], rmL[32];
    int pix0 = blockIdx.x * 32;
    int b = pix0 >> 12;
    int l0 = pix0 & 4095;
    const __hip_bfloat16* y0 = ybuf + (size_t)(0 * BB + b) * LL * DI;
    const __hip_bfloat16* y1 = ybuf + (size_t)(1 * BB + b) * LL * DI;
    const __hip_bfloat16* y2 = ybuf + (size_t)(2 * BB + b) * LL * DI;
    const __hip_bfloat16* y3 = ybuf + (size_t)(3 * BB + b) * LL * DI;
    for (int i = threadIdx.x; i < 32 * DI; i += 256){
        int c = i % DI, p = i / DI;
        int l = l0 + p; int hh = l >> 6, ww = l & 63;
        int lT = (ww << 6) | hh;
        float s = __bfloat162float(y0[(size_t)l * DI + c])
                + __bfloat162float(y2[(size_t)(LL - 1 - l) * DI + c])
                + __bfloat162float(y1[(size_t)lT * DI + c])
                + __bfloat162float(y3[(size_t)(LL - 1 - lT) * DI + c]);
        yT[c][p] = s;
    }
    __syncthreads();
    {
        int p = threadIdx.x >> 3, cg = threadIdx.x & 7;
        float s = 0.f, s2 = 0.f;
        for (int c = cg; c < DI; c += 8){ float v = yT[c][p]; s += v; s2 = fmaf(v, v, s2); }
        s += __shfl_xor(s, 1, 64); s2 += __shfl_xor(s2, 1, 64);
        s += __shfl_xor(s, 2, 64); s2 += __shfl_xor(s2, 2, 64);
        s += __shfl_xor(s, 4, 64); s2 += __shfl_xor(s2, 4, 64);
        if (cg == 0){
            float mu = s * (1.f / DI);
            float var = s2 * (1.f / DI) - mu * mu;
            float rs = rsqrtf(var + 1e-5f);
            rsL[p] = rs; rmL[p] = rs * mu;
        }
    }
    __syncthreads();
    if (threadIdx.x < 192){
        int mg = threadIdx.x % 24, pg = threadIdx.x / 24;  // 8 pixgroups x 24 mgroups
        int p0 = pg * 4;
        float4 acc[4];
        #pragma unroll
        for (int i = 0; i < 4; ++i) acc[i] = make_float4(0.f, 0.f, 0.f, 0.f);
        const float* wcol = wg + mg * 4;
        for (int c0 = 0; c0 < DI; c0 += 8){
            float4 wv[8], yv[8];
            #pragma unroll
            for (int j = 0; j < 8; ++j){
                wv[j] = *(const float4*)(wcol + (c0 + j) * DM);
                yv[j] = *(const float4*)(&yT[c0 + j][p0]);
            }
            #pragma unroll
            for (int j = 0; j < 8; ++j){
                float ys[4] = {yv[j].x, yv[j].y, yv[j].z, yv[j].w};
                #pragma unroll
                for (int pi = 0; pi < 4; ++pi){
                    acc[pi].x = fmaf(ys[pi], wv[j].x, acc[pi].x);
                    acc[pi].y = fmaf(ys[pi], wv[j].y, acc[pi].y);
                    acc[pi].z = fmaf(ys[pi], wv[j].z, acc[pi].z);
                    acc[pi].w = fmaf(ys[pi], wv[j].w, acc[pi].w);
                }
            }
        }
        float4 sg4 = *(const float4*)(sgbw + mg * 4);
        float4 bw4 = *(const float4*)(sgbw + DM + mg * 4);
        #pragma unroll
        for (int pi = 0; pi < 4; ++pi){
            float rs = rsL[p0 + pi], rm = rmL[p0 + pi];
            float4 o;
            o.x = fmaf(acc[pi].x, rs, fmaf(-rm, sg4.x, bw4.x));
            o.y = fmaf(acc[pi].y, rs, fmaf(-rm, sg4.y, bw4.y));
            o.z = fmaf(acc[pi].z, rs, fmaf(-rm, sg4.z, bw4.z));
            o.w = fmaf(acc[pi].w, rs, fmaf(-rm, sg4.w, bw4.w));
            *(float4*)(out + (size_t)(pix0 + p0 + pi) * DM + mg * 4) = o;
        }
    }
}

extern "C" void kernel_launch(void* const* d_in, const int* in_sizes, int n_in,
                              void* d_out, int out_size, void* d_ws, size_t ws_size,
                              hipStream_t stream){
    const float* x      = (const float*)d_in[0];
    const float* w_in   = (const float*)d_in[1];
    const float* w_conv = (const float*)d_in[2];
    const float* b_conv = (const float*)d_in[3];
    const float* xproj  = (const float*)d_in[4];
    const float* A_logs = (const float*)d_in[5];
    const float* Ds     = (const float*)d_in[6];
    const float* dtbias = (const float*)d_in[7];
    const float* ln_g   = (const float*)d_in[8];
    const float* ln_b   = (const float*)d_in[9];
    const float* w_out  = (const float*)d_in[10];
    float* out = (float*)d_out;

    // workspace layout (floats):
    float* ws   = (float*)d_ws;
    float* xi   = ws;                      // 6,291,456
    float* xiT  = xi + 6291456;            // 6,291,456
    float* Sb   = xiT + 6291456;           // 6,291,456
    float* Pb   = Sb + 6291456;            // 16,384
    float* WpR  = Pb + 16384;              // 30,720
    float* wg   = WpR + 30720;             // 18,432
    float* sgbw = wg + 18432;              // 192
    float* big  = sgbw + 192;              // union: xw (6,291,456) / rec (6,291,456)
    float* xw   = big;
    float* rec  = big;
    __hip_bfloat16* ybuf = (__hip_bfloat16*)(big + 6291456);  // 25,165,824 bf16

    k0p<<<193, 256, 0, stream>>>(xproj, ln_g, ln_b, w_out, WpR, wg, sgbw);
    k1_inproj<<<1024, 384, 0, stream>>>(x, w_in, xw);
    k2_conv<<<6144, 256, 0, stream>>>(xw, w_conv, b_conv, xi, xiT);
    k3seq<<<dim3(64, 2, BB), 320, 0, stream>>>(xi, xiT, WpR, A_logs, dtbias, rec);
    k4a<<<dim3(NCH, KKK, BB), 192, 0, stream>>>(xi, xiT, rec, Pb, Sb);
    k4b<<<384, 256, 0, stream>>>(Pb, Sb);
    k4c<<<dim3(NCH, KKK, BB), 192, 0, stream>>>(xi, xiT, rec, Ds, Sb, ybuf);
    k5_out<<<1024, 256, 0, stream>>>(ybuf, wg, sgbw, out);
}

// Round 7
// 276.720 us; speedup vs baseline: 1.0453x; 1.0251x over previous
//
#include <hip/hip_runtime.h>
#include <hip/hip_bf16.h>

#define BB 8
#define LL 4096
#define DM 96
#define DI 192
#define RRR 6
#define DHH 32
#define KKK 4
#define NNN 16
#define KRR 24
#define NCH 64
#define TT 64
#define RST 48   // rec record layout (floats): dt 0-5 | pad | dec 8-13 | pad | B 16-31 | C 32-47

typedef unsigned short u16;
typedef __attribute__((ext_vector_type(8))) __bf16 bf16x8;
typedef __attribute__((ext_vector_type(4))) float f32x4;

__device__ __forceinline__ float softplus_f(float x){
    float ax = fabsf(x);
    return fmaxf(x, 0.f) + __logf(1.f + __expf(-ax));
}
__device__ __forceinline__ float silu_f(float x){ return x / (1.f + __expf(-x)); }

__device__ __forceinline__ void split_bf16(float v, u16& h, u16& l){
    __bf16 hb = (__bf16)v;
    h = __builtin_bit_cast(u16, hb);
    float r = v - (float)hb;
    l = __builtin_bit_cast(u16, (__bf16)r);
}

// ---------------- K0p: prep — WhB/WlB[2][80][192] bf16 split, wg, sg/bw ----------------
// per-z 80 cols = [dir_a 40 | dir_b 40]; per-dir 40: dt 0-5, pad 6-7, B 8-23, C 24-39.
__global__ void k0p(const float* __restrict__ W, const float* __restrict__ g,
                    const float* __restrict__ bta, const float* __restrict__ w_out,
                    u16* __restrict__ WhB, u16* __restrict__ WlB,
                    float* __restrict__ wg, float* __restrict__ sgbw){
    int i = blockIdx.x * 256 + threadIdx.x;
    if (i < 2 * 80 * 192){
        int k = i % 192; int n80 = i / 192; int z = n80 / 80; int n = n80 % 80;
        int sub = n / 40, nc = n % 40;
        int dir = (z == 0) ? (sub ? 2 : 0) : (sub ? 3 : 1);
        float v = 0.f;
        if (nc < 6) v = W[(dir * 38 + nc) * DI + k];
        else if (nc >= 8) v = W[(dir * 38 + (nc - 2)) * DI + k];
        u16 h, l; split_bf16(v, h, l);
        WhB[i] = h; WlB[i] = l;
    } else if (i < 30720 + DI * DM){
        int j = i - 30720; int c = j / DM;
        wg[j] = w_out[j] * g[c];
    } else if (i < 30720 + DI * DM + DM){
        int m = i - (30720 + DI * DM);
        float s = 0.f, t = 0.f;
        for (int c = 0; c < DI; ++c){
            float w = w_out[c * DM + m];
            s = fmaf(g[c], w, s);
            t = fmaf(bta[c], w, t);
        }
        sgbw[m] = s; sgbw[DM + m] = t;
    }
}

// ---------------- K1: xw = x @ w_in, 32-pix tiles ----------------
__global__ __launch_bounds__(384) void k1_inproj(const float* __restrict__ x,
                                                 const float* __restrict__ w_in,
                                                 float* __restrict__ xw){
    __shared__ float xT[DM][36];
    int pix0 = blockIdx.x * 32;
    for (int i = threadIdx.x; i < 32 * 24; i += 384){
        int c4 = i % 24, p = i / 24;
        float4 v = *(const float4*)(x + (size_t)(pix0 + p) * DM + c4 * 4);
        xT[c4 * 4 + 0][p] = v.x; xT[c4 * 4 + 1][p] = v.y;
        xT[c4 * 4 + 2][p] = v.z; xT[c4 * 4 + 3][p] = v.w;
    }
    __syncthreads();
    int cg = threadIdx.x % 48, pg = threadIdx.x / 48;   // 8 pixgroups(4 pix) x 48 cgroups
    int p0 = pg * 4;
    float4 acc[4];
    #pragma unroll
    for (int i = 0; i < 4; ++i) acc[i] = make_float4(0.f, 0.f, 0.f, 0.f);
    const float* wcol = w_in + cg * 4;
    for (int d0 = 0; d0 < DM; d0 += 8){
        float4 wv[8], xv[8];
        #pragma unroll
        for (int j = 0; j < 8; ++j){
            wv[j] = *(const float4*)(wcol + (d0 + j) * DI);
            xv[j] = *(const float4*)(&xT[d0 + j][p0]);
        }
        #pragma unroll
        for (int j = 0; j < 8; ++j){
            float xs[4] = {xv[j].x, xv[j].y, xv[j].z, xv[j].w};
            #pragma unroll
            for (int pi = 0; pi < 4; ++pi){
                acc[pi].x = fmaf(xs[pi], wv[j].x, acc[pi].x);
                acc[pi].y = fmaf(xs[pi], wv[j].y, acc[pi].y);
                acc[pi].z = fmaf(xs[pi], wv[j].z, acc[pi].z);
                acc[pi].w = fmaf(xs[pi], wv[j].w, acc[pi].w);
            }
        }
    }
    #pragma unroll
    for (int pi = 0; pi < 4; ++pi)
        *(float4*)(xw + (size_t)(pix0 + p0 + pi) * DI + cg * 4) = acc[pi];
}

// ---------------- K2: xi = silu(dwconv3x3(xw) + b_conv); also write transposed xiT -----------
__global__ void k2_conv(const float* __restrict__ xw, const float* __restrict__ wc,
                        const float* __restrict__ bc, float* __restrict__ xi,
                        float* __restrict__ xiT){
    int gid = blockIdx.x * 256 + threadIdx.x;   // BB*LL*48 threads, float4 over channels
    int c4 = gid % 48; int pix = gid / 48;
    int b = pix >> 12; int l = pix & 4095; int h = l >> 6; int w = l & 63;
    int c = c4 * 4;
    float4 acc = *(const float4*)(bc + c);
    #pragma unroll
    for (int dh = 0; dh < 3; ++dh){
        int hh = h + dh - 1; if ((unsigned)hh >= 64u) continue;
        #pragma unroll
        for (int dw = 0; dw < 3; ++dw){
            int ww2 = w + dw - 1; if ((unsigned)ww2 >= 64u) continue;
            float4 tap = *(const float4*)(xw + (size_t)((b << 12) + (hh << 6) + ww2) * DI + c);
            float4 wv  = *(const float4*)(wc + (dh * 3 + dw) * DI + c);
            acc.x = fmaf(tap.x, wv.x, acc.x);
            acc.y = fmaf(tap.y, wv.y, acc.y);
            acc.z = fmaf(tap.z, wv.z, acc.z);
            acc.w = fmaf(tap.w, wv.w, acc.w);
        }
    }
    acc.x = silu_f(acc.x); acc.y = silu_f(acc.y); acc.z = silu_f(acc.z); acc.w = silu_f(acc.w);
    *(float4*)(xi + (size_t)pix * DI + c) = acc;
    int lT = ((l & 63) << 6) | (l >> 6);
    *(float4*)(xiT + (size_t)((b << 12) + lT) * DI + c) = acc;
}

// ---------------- K3seq v5 (MFMA bf16x3): z=0: xi -> dirs{0,2}; z=1: xiT -> dirs{1,3} --------
// 64-pix tiles, 256 threads = 4 waves, each wave one 16-pix M-tile x 80 cols.
// X split to bf16 hi/lo in LDS; W prepacked bf16 hi/lo [z][n][k] read via L1/L2.
// D = Xh@Wh + Xl@Wh + Xh@Wl  (bf16x3, ~fp32 accuracy).
__global__ __launch_bounds__(256) void k3seq(const float* __restrict__ xi,
                                             const float* __restrict__ xiT,
                                             const u16* __restrict__ WhB,
                                             const u16* __restrict__ WlB,
                                             const float* __restrict__ A_logs,
                                             const float* __restrict__ dtb,
                                             float* __restrict__ rec){
    __shared__ u16 Xh[64][104];
    __shared__ u16 Xl[64][104];
    int z = blockIdx.y, b = blockIdx.z;
    int l0 = blockIdx.x * 64;
    const float* src = (z ? xiT : xi) + ((((size_t)b) << 12) + l0) * DI;
    int wv = threadIdx.x >> 6, lane = threadIdx.x & 63;
    int quad = lane >> 4, mi = lane & 15;
    int m0 = wv * 16;
    f32x4 acc[5];
    #pragma unroll
    for (int nt = 0; nt < 5; ++nt) acc[nt] = (f32x4){0.f, 0.f, 0.f, 0.f};
    const u16* wh = WhB + (size_t)z * 80 * 192;
    const u16* wl = WlB + (size_t)z * 80 * 192;
    #pragma unroll
    for (int half = 0; half < 2; ++half){
        __syncthreads();
        for (int i = threadIdx.x; i < 1536; i += 256){   // 64 pix x 24 float4 (96 ch)
            int c4 = i % 24, p = i / 24;
            float4 v = *(const float4*)(src + (size_t)p * DI + half * 96 + c4 * 4);
            u16 h0, h1, h2, h3, q0, q1, q2, q3;
            split_bf16(v.x, h0, q0); split_bf16(v.y, h1, q1);
            split_bf16(v.z, h2, q2); split_bf16(v.w, h3, q3);
            *(ushort4*)&Xh[p][c4 * 4] = make_ushort4(h0, h1, h2, h3);
            *(ushort4*)&Xl[p][c4 * 4] = make_ushort4(q0, q1, q2, q3);
        }
        __syncthreads();
        #pragma unroll
        for (int kt = 0; kt < 3; ++kt){
            int ko = kt * 32 + quad * 8;
            bf16x8 ah = *(const bf16x8*)&Xh[m0 + mi][ko];
            bf16x8 al = *(const bf16x8*)&Xl[m0 + mi][ko];
            int kg = half * 96 + ko;
            #pragma unroll
            for (int nt = 0; nt < 5; ++nt){
                const size_t woff = (size_t)(nt * 16 + mi) * 192 + kg;
                bf16x8 bh = *(const bf16x8*)(wh + woff);
                bf16x8 bl = *(const bf16x8*)(wl + woff);
                acc[nt] = __builtin_amdgcn_mfma_f32_16x16x32_bf16(ah, bh, acc[nt], 0, 0, 0);
                acc[nt] = __builtin_amdgcn_mfma_f32_16x16x32_bf16(al, bh, acc[nt], 0, 0, 0);
                acc[nt] = __builtin_amdgcn_mfma_f32_16x16x32_bf16(ah, bl, acc[nt], 0, 0, 0);
            }
        }
    }
    // epilogue: D row = quad*4+i (pixel within M-tile), col = mi (within N-tile)
    #pragma unroll
    for (int nt = 0; nt < 5; ++nt){
        int nc = nt * 16 + mi;             // 0..79
        int sub = nc / 40;
        int dir = (z == 0) ? (sub ? 2 : 0) : (sub ? 3 : 1);
        int c40 = nc % 40;
        float* rb = rec + (size_t)(b * KKK + dir) * LL * RST;
        bool isdt = (c40 < 6);
        bool ispad = (c40 == 6) | (c40 == 7);
        float Ac = 0.f, bc = 0.f;
        if (isdt){ Ac = -__expf(A_logs[dir * RRR + c40]); bc = dtb[dir * RRR + c40]; }
        #pragma unroll
        for (int i = 0; i < 4; ++i){
            int l = l0 + m0 + quad * 4 + i;
            int t = (sub == 0) ? l : (LL - 1 - l);
            float v = acc[nt][i];
            float* rw = rb + (size_t)t * RST;
            if (isdt){
                float dt = softplus_f(v + bc);
                rw[c40] = dt;
                rw[c40 + 8] = __expf(dt * Ac);
            } else if (!ispad){
                rw[c40 + 8] = v;           // B: 8-23 -> 16-31; C: 24-39 -> 32-47
            }
        }
    }
}

// ---------------- K4a: per-chunk local scan -> P, S  (all streams constant-stride) ------------
__global__ __launch_bounds__(192) void k4a(const float* __restrict__ xi, const float* __restrict__ xiT,
                                           const float* __restrict__ rec,
                                           float* __restrict__ Pb, float* __restrict__ Sb){
    int chunk = blockIdx.x, k = blockIdx.y, b = blockIdx.z;
    int r = threadIdx.x >> 5, d = threadIdx.x & 31;
    int kr = k * RRR + r;
    const float* rp = rec + ((size_t)(b * KKK + k) * LL + chunk * TT) * RST;
    const float* xb = ((k & 1) ? xiT : xi) + (((size_t)b) << 12) * DI + r * DHH + d;
    const float* up; ptrdiff_t ust;
    if (k < 2){ up = xb + (size_t)(chunk * TT) * DI;          ust = DI;  }
    else      { up = xb + (size_t)(LL - 1 - chunk * TT) * DI; ust = -(ptrdiff_t)DI; }
    float h[NNN];
    #pragma unroll
    for (int n = 0; n < NNN; ++n) h[n] = 0.f;
    float P = 1.f;
    #pragma unroll 4
    for (int tt = 0; tt < TT; ++tt){
        float dt  = rp[r];
        float dec = rp[8 + r];
        float u = *up;
        float xu = dt * u;
        P *= dec;
        float Bv[NNN];
        *(float4*)(Bv + 0)  = *(const float4*)(rp + 16);
        *(float4*)(Bv + 4)  = *(const float4*)(rp + 20);
        *(float4*)(Bv + 8)  = *(const float4*)(rp + 24);
        *(float4*)(Bv + 12) = *(const float4*)(rp + 28);
        #pragma unroll
        for (int n = 0; n < NNN; ++n) h[n] = fmaf(dec, h[n], xu * Bv[n]);
        rp += RST; up += ust;
    }
    size_t sb = (((size_t)(b * KRR + kr) * NCH + chunk) * DHH + d) * NNN;
    #pragma unroll
    for (int n = 0; n < NNN; ++n) Sb[sb + n] = h[n];
    if (d == 0) Pb[(size_t)(b * KRR + kr) * NCH + chunk] = P;
}

// ---------------- K4b: cross-chunk exclusive scan (in-place), split grid ----------------
__global__ __launch_bounds__(256) void k4b(const float* __restrict__ Pb, float* __restrict__ Sb){
    int scan = blockIdx.x >> 1;        // b*KRR + kr
    int half = blockIdx.x & 1;
    int tid = half * 256 + threadIdx.x;   // 512 = d*16 + n
    size_t base = (size_t)scan * NCH * 512 + tid;
    const float* Pp = Pb + (size_t)scan * NCH;
    float s[NCH];
    #pragma unroll
    for (int c = 0; c < NCH; ++c) s[c] = Sb[base + (size_t)c * 512];
    float hb = 0.f;
    #pragma unroll
    for (int c = 0; c < NCH; ++c){
        float nv = fmaf(Pp[c], hb, s[c]);
        Sb[base + (size_t)c * 512] = hb;
        hb = nv;
    }
}

// ---------------- K4c: replay from h_init, emit y in sequence order (bf16) ----------------
__global__ __launch_bounds__(192) void k4c(const float* __restrict__ xi, const float* __restrict__ xiT,
                                           const float* __restrict__ rec,
                                           const float* __restrict__ Ds, const float* __restrict__ Sb,
                                           __hip_bfloat16* __restrict__ ybuf){
    int chunk = blockIdx.x, k = blockIdx.y, b = blockIdx.z;
    int r = threadIdx.x >> 5, d = threadIdx.x & 31;
    int kr = k * RRR + r;
    float Dv = Ds[kr * DHH + d];
    float h[NNN];
    size_t sb = (((size_t)(b * KRR + kr) * NCH + chunk) * DHH + d) * NNN;
    #pragma unroll
    for (int n = 0; n < NNN; ++n) h[n] = Sb[sb + n];
    const float* rp = rec + ((size_t)(b * KKK + k) * LL + chunk * TT) * RST;
    const float* xb = ((k & 1) ? xiT : xi) + (((size_t)b) << 12) * DI + r * DHH + d;
    const float* up; ptrdiff_t ust;
    if (k < 2){ up = xb + (size_t)(chunk * TT) * DI;          ust = DI;  }
    else      { up = xb + (size_t)(LL - 1 - chunk * TT) * DI; ust = -(ptrdiff_t)DI; }
    __hip_bfloat16* yp = ybuf + ((size_t)(k * BB + b) * LL + chunk * TT) * DI + r * DHH + d;
    #pragma unroll 2
    for (int tt = 0; tt < TT; ++tt){
        float dt  = rp[r];
        float dec = rp[8 + r];
        float u = *up;
        float xu = dt * u;
        float Bv[NNN], Cv[NNN];
        *(float4*)(Bv + 0)  = *(const float4*)(rp + 16);
        *(float4*)(Bv + 4)  = *(const float4*)(rp + 20);
        *(float4*)(Bv + 8)  = *(const float4*)(rp + 24);
        *(float4*)(Bv + 12) = *(const float4*)(rp + 28);
        *(float4*)(Cv + 0)  = *(const float4*)(rp + 32);
        *(float4*)(Cv + 4)  = *(const float4*)(rp + 36);
        *(float4*)(Cv + 8)  = *(const float4*)(rp + 40);
        *(float4*)(Cv + 12) = *(const float4*)(rp + 44);
        float y = 0.f;
        #pragma unroll
        for (int n = 0; n < NNN; ++n){
            h[n] = fmaf(dec, h[n], xu * Bv[n]);
            y = fmaf(h[n], Cv[n], y);
        }
        y = fmaf(u, Dv, y);
        *yp = __float2bfloat16(y);
        rp += RST; up += ust; yp += DI;
    }
}

// ---------------- K5: gather 4 sequence-ordered y's + fused LayerNorm + out-proj ----------------
__global__ __launch_bounds__(256) void k5_out(const __hip_bfloat16* __restrict__ ybuf,
                       const float* __restrict__ wg, const float* __restrict__ sgbw,
                       float* __restrict__ out){
    __shared__ float yT[DI][36];
    __shared__ float rsL[32], rmL[32];
    int pix0 = blockIdx.x * 32;
    int b = pix0 >> 12;
    int l0 = pix0 & 4095;
    const __hip_bfloat16* y0 = ybuf + (size_t)(0 * BB + b) * LL * DI;
    const __hip_bfloat16* y1 = ybuf + (size_t)(1 * BB + b) * LL * DI;
    const __hip_bfloat16* y2 = ybuf + (size_t)(2 * BB + b) * LL * DI;
    const __hip_bfloat16* y3 = ybuf + (size_t)(3 * BB + b) * LL * DI;
    for (int i = threadIdx.x; i < 32 * DI; i += 256){
        int c = i % DI, p = i / DI;
        int l = l0 + p; int hh = l >> 6, ww = l & 63;
        int lT = (ww << 6) | hh;
        float s = __bfloat162float(y0[(size_t)l * DI + c])
                + __bfloat162float(y2[(size_t)(LL - 1 - l) * DI + c])
                + __bfloat162float(y1[(size_t)lT * DI + c])
                + __bfloat162float(y3[(size_t)(LL - 1 - lT) * DI + c]);
        yT[c][p] = s;
    }
    __syncthreads();
    {
        int p = threadIdx.x >> 3, cg = threadIdx.x & 7;
        float s = 0.f, s2 = 0.f;
        for (int c = cg; c < DI; c += 8){ float v = yT[c][p]; s += v; s2 = fmaf(v, v, s2); }
        s += __shfl_xor(s, 1, 64); s2 += __shfl_xor(s2, 1, 64);
        s += __shfl_xor(s, 2, 64); s2 += __shfl_xor(s2, 2, 64);
        s += __shfl_xor(s, 4, 64); s2 += __shfl_xor(s2, 4, 64);
        if (cg == 0){
            float mu = s * (1.f / DI);
            float var = s2 * (1.f / DI) - mu * mu;
            float rs = rsqrtf(var + 1e-5f);
            rsL[p] = rs; rmL[p] = rs * mu;
        }
    }
    __syncthreads();
    if (threadIdx.x < 192){
        int mg = threadIdx.x % 24, pg = threadIdx.x / 24;  // 8 pixgroups x 24 mgroups
        int p0 = pg * 4;
        float4 acc[4];
        #pragma unroll
        for (int i = 0; i < 4; ++i) acc[i] = make_float4(0.f, 0.f, 0.f, 0.f);
        const float* wcol = wg + mg * 4;
        for (int c0 = 0; c0 < DI; c0 += 8){
            float4 wv[8], yv[8];
            #pragma unroll
            for (int j = 0; j < 8; ++j){
                wv[j] = *(const float4*)(wcol + (c0 + j) * DM);
                yv[j] = *(const float4*)(&yT[c0 + j][p0]);
            }
            #pragma unroll
            for (int j = 0; j < 8; ++j){
                float ys[4] = {yv[j].x, yv[j].y, yv[j].z, yv[j].w};
                #pragma unroll
                for (int pi = 0; pi < 4; ++pi){
                    acc[pi].x = fmaf(ys[pi], wv[j].x, acc[pi].x);
                    acc[pi].y = fmaf(ys[pi], wv[j].y, acc[pi].y);
                    acc[pi].z = fmaf(ys[pi], wv[j].z, acc[pi].z);
                    acc[pi].w = fmaf(ys[pi], wv[j].w, acc[pi].w);
                }
            }
        }
        float4 sg4 = *(const float4*)(sgbw + mg * 4);
        float4 bw4 = *(const float4*)(sgbw + DM + mg * 4);
        #pragma unroll
        for (int pi = 0; pi < 4; ++pi){
            float rs = rsL[p0 + pi], rm = rmL[p0 + pi];
            float4 o;
            o.x = fmaf(acc[pi].x, rs, fmaf(-rm, sg4.x, bw4.x));
            o.y = fmaf(acc[pi].y, rs, fmaf(-rm, sg4.y, bw4.y));
            o.z = fmaf(acc[pi].z, rs, fmaf(-rm, sg4.z, bw4.z));
            o.w = fmaf(acc[pi].w, rs, fmaf(-rm, sg4.w, bw4.w));
            *(float4*)(out + (size_t)(pix0 + p0 + pi) * DM + mg * 4) = o;
        }
    }
}

extern "C" void kernel_launch(void* const* d_in, const int* in_sizes, int n_in,
                              void* d_out, int out_size, void* d_ws, size_t ws_size,
                              hipStream_t stream){
    const float* x      = (const float*)d_in[0];
    const float* w_in   = (const float*)d_in[1];
    const float* w_conv = (const float*)d_in[2];
    const float* b_conv = (const float*)d_in[3];
    const float* xproj  = (const float*)d_in[4];
    const float* A_logs = (const float*)d_in[5];
    const float* Ds     = (const float*)d_in[6];
    const float* dtbias = (const float*)d_in[7];
    const float* ln_g   = (const float*)d_in[8];
    const float* ln_b   = (const float*)d_in[9];
    const float* w_out  = (const float*)d_in[10];
    float* out = (float*)d_out;

    // workspace layout (floats):
    float* ws   = (float*)d_ws;
    float* xi   = ws;                      // 6,291,456
    float* xiT  = xi + 6291456;            // 6,291,456
    float* Sb   = xiT + 6291456;           // 6,291,456
    float* Pb   = Sb + 6291456;            // 16,384
    float* wbase= Pb + 16384;              // 30,720 floats total for WhB+WlB (u16 each)
    u16*   WhB  = (u16*)wbase;             // 30,720 u16 (= 15,360 floats)
    u16*   WlB  = (u16*)(wbase + 15360);   // 30,720 u16
    float* wg   = wbase + 30720;           // 18,432
    float* sgbw = wg + 18432;              // 192
    float* big  = sgbw + 192;              // union: xw (6,291,456) / rec (6,291,456)
    float* xw   = big;
    float* rec  = big;
    __hip_bfloat16* ybuf = (__hip_bfloat16*)(big + 6291456);  // 25,165,824 bf16

    k0p<<<193, 256, 0, stream>>>(xproj, ln_g, ln_b, w_out, WhB, WlB, wg, sgbw);
    k1_inproj<<<1024, 384, 0, stream>>>(x, w_in, xw);
    k2_conv<<<6144, 256, 0, stream>>>(xw, w_conv, b_conv, xi, xiT);
    k3seq<<<dim3(64, 2, BB), 256, 0, stream>>>(xi, xiT, WhB, WlB, A_logs, dtbias, rec);
    k4a<<<dim3(NCH, KKK, BB), 192, 0, stream>>>(xi, xiT, rec, Pb, Sb);
    k4b<<<384, 256, 0, stream>>>(Pb, Sb);
    k4c<<<dim3(NCH, KKK, BB), 192, 0, stream>>>(xi, xiT, rec, Ds, Sb, ybuf);
    k5_out<<<1024, 256, 0, stream>>>(ybuf, wg, sgbw, out);
}